// Round 4
// baseline (6731.542 us; speedup 1.0000x reference)
//
#include <hip/hip_runtime.h>

typedef unsigned short ushort_t;
typedef unsigned int uint_t;
typedef short v8s __attribute__((ext_vector_type(8)));
typedef float v4f __attribute__((ext_vector_type(4)));

__device__ __forceinline__ float b2f(ushort_t u) {
    uint_t x = ((uint_t)u) << 16;
    float f;
    __builtin_memcpy(&f, &x, 4);
    return f;
}
__device__ __forceinline__ ushort_t f2b(float f) {
    uint_t x;
    __builtin_memcpy(&x, &f, 4);
    uint_t r = (x + 0x7FFFu + ((x >> 16) & 1u)) >> 16;
    return (ushort_t)r;
}

// ---------------------------------------------------------------------------
__global__ void k_cvt(const float* __restrict__ src, ushort_t* __restrict__ dst, int n) {
    int i = blockIdx.x * 256 + threadIdx.x;
    if (i < n) dst[i] = f2b(src[i]);
}

__global__ void k_zero(int* __restrict__ p, int n) {
    int i = blockIdx.x * 256 + threadIdx.x;
    if (i < n) p[i] = 0;
}

// ---------------------------------------------------------------------------
// K1: per-(b,c) scan over t: values(f32), masks/deltas/gamma_x (bf16). [T,B,C]
// ---------------------------------------------------------------------------
__global__ void k_pre(const float* __restrict__ data,
                      const float* __restrict__ Wgx,
                      const float* __restrict__ bgx,
                      float* __restrict__ values, ushort_t* __restrict__ masks,
                      ushort_t* __restrict__ deltas, ushort_t* __restrict__ gammax) {
    int id = blockIdx.x * 256 + threadIdx.x;   // 0..16383 = b*64+c
    int b = id >> 6, c = id & 63;
    float wd = Wgx[c * 64 + c];
    float bg = bgx[c];
    float d_prev = 0.f, m_prev = 0.f;
    for (int t = 0; t < 256; ++t) {
        float x = data[b * 16384 + t * 64 + c];
        bool nan = (x != x);
        float m = nan ? 0.f : 1.f;
        float v = nan ? 0.f : x;
        float d;
        if (t == 0) d = 0.f;
        else if (t == 1) d = 1.f;
        else d = (m_prev == 1.f) ? 1.f : d_prev + 1.f;
        float s = d * wd + bg;
        float gx = (s > 0.f) ? __expf(-s) : 1.f;
        int o = t * 16384 + id;
        values[o] = v;
        masks[o]  = f2b(m);
        deltas[o] = f2b(d);
        gammax[o] = f2b(gx);
        m_prev = m; d_prev = d;
    }
}

// ---------------------------------------------------------------------------
// K2: alpha[t,b,i]
// ---------------------------------------------------------------------------
__global__ void k_alpha(const ushort_t* __restrict__ gammax,
                        const ushort_t* __restrict__ masks,
                        const float* __restrict__ Wcomb,
                        const float* __restrict__ bcomb,
                        ushort_t* __restrict__ alpha) {
    int id = blockIdx.x * 256 + threadIdx.x;
    int i = id & 63;
    int tb = id >> 6;
    const ushort_t* gx = gammax + tb * 64;
    const ushort_t* mk = masks + tb * 64;
    const float* w0 = Wcomb + i * 128;
    float acc = bcomb[i];
#pragma unroll
    for (int j0 = 0; j0 < 64; j0 += 8) {
        v8s g = *(const v8s*)(gx + j0);
        v8s m = *(const v8s*)(mk + j0);
#pragma unroll
        for (int j = 0; j < 8; ++j) {
            acc += b2f((ushort_t)g[j]) * w0[j0 + j];
            acc += b2f((ushort_t)m[j]) * w0[64 + j0 + j];
        }
    }
    alpha[id] = f2b(acc);
}

// ---------------------------------------------------------------------------
// Persistent step kernel: 256 wgs (rb 0..15, cb 0..15), all 256 time steps
// inside, weights in VGPRs, per-rb 16-wg device-atomic barrier between steps,
// h ping-pong through global, cell state in registers.
// PLAIN launch: grid(256) <= CU count and LDS<64KB -> all blocks resident;
// no cooperative launch needed (we never use grid_sync).
// ---------------------------------------------------------------------------
__global__ __launch_bounds__(256, 1) void k_run(
    const float* __restrict__ values, const ushort_t* __restrict__ masks,
    const ushort_t* __restrict__ deltas, const ushort_t* __restrict__ alpha,
    const ushort_t* __restrict__ Wih, const ushort_t* __restrict__ Whh,
    const float* __restrict__ bih, const float* __restrict__ bhh,
    const ushort_t* __restrict__ Wgh, const float* __restrict__ bgh,
    const ushort_t* __restrict__ Whist, const float* __restrict__ bhist,
    const ushort_t* __restrict__ Wfeat, const float* __restrict__ bfeat,
    ushort_t* __restrict__ hA, ushort_t* __restrict__ hB,
    int* __restrict__ bar, float* __restrict__ out) {
    __shared__ __attribute__((aligned(16))) ushort_t hlds[16 * 520];   // h_dec bf16
    __shared__ __attribute__((aligned(16))) ushort_t inplds[16 * 136]; // [c_c | m]
    __shared__ __attribute__((aligned(16))) ushort_t xclds[16 * 72];   // x_c bf16
    __shared__ __attribute__((aligned(16))) ushort_t d1b[16 * 72];     // delta_{t+1} bf16
    __shared__ __attribute__((aligned(16))) float xh_lds[16 * 68];
    __shared__ __attribute__((aligned(16))) float zh_lds[16 * 68];
    __shared__ __attribute__((aligned(16))) float gl[4 * 16 * 36];     // gate planes
    __shared__ __attribute__((aligned(16))) float gam[16 * 36];        // gamma_h tile

    int tid = threadIdx.x;
    int w = tid >> 6;
    int lane = tid & 63;
    int l15 = lane & 15, quad = lane >> 4;
    int wg = blockIdx.x;
    int rb = wg & 15, cb = wg >> 4;
    int b0 = rb * 16;

    // ---- one-time: persistent weight fragments in VGPRs ----
    v8s whhF[2][16], wihF[2][4], whisF[16], wfF[2], wghF[2] = {};
    float biasv[2];
#pragma unroll
    for (int nt2 = 0; nt2 < 2; ++nt2) {
        int hc = cb * 32 + nt2 * 16 + l15;
        int rW = w * 512 + hc;
        const ushort_t* whrow = Whh + rW * 512;
        const ushort_t* wirow = Wih + rW * 128;
#pragma unroll
        for (int kt = 0; kt < 16; ++kt)
            whhF[nt2][kt] = *(const v8s*)(whrow + kt * 32 + quad * 8);
#pragma unroll
        for (int kt = 0; kt < 4; ++kt)
            wihF[nt2][kt] = *(const v8s*)(wirow + kt * 32 + quad * 8);
        biasv[nt2] = bih[rW] + bhh[rW];
    }
    {
        int ncol = w * 16 + l15;
        const ushort_t* hrow = Whist + ncol * 512;
#pragma unroll
        for (int kt = 0; kt < 16; ++kt)
            whisF[kt] = *(const v8s*)(hrow + kt * 32 + quad * 8);
        const ushort_t* frow = Wfeat + ncol * 64;
#pragma unroll
        for (int kt = 0; kt < 2; ++kt) {
            int k0 = kt * 32 + quad * 8;
            v8s bb = *(const v8s*)(frow + k0);
#pragma unroll
            for (int j = 0; j < 8; ++j)
                if (k0 + j == ncol) bb[j] = 0;   // zero diagonal
            wfF[kt] = bb;
        }
    }
    float bghv = 0.f;
    if (w < 2) {
        int gcol = cb * 32 + w * 16 + l15;
        const ushort_t* grow = Wgh + gcol * 64;
#pragma unroll
        for (int kt = 0; kt < 2; ++kt)
            wghF[kt] = *(const v8s*)(grow + kt * 32 + quad * 8);
        bghv = bgh[gcol];
    }
    float bhistv = bhist[tid & 63];
    float bfeatv = bfeat[tid & 63];

    float c_reg[2] = {0.f, 0.f};
    ushort_t* bufs[2] = {hA, hB};

    for (int t = 0; t < 256; ++t) {
        // ---- wait for step t-1's h writes (per-rb barrier, 16 wgs) ----
        if (t > 0) {
            if (tid == 0) {
                int cnt = 0;
                while (__hip_atomic_load(&bar[rb * 256 + (t - 1)],
                                         __ATOMIC_ACQUIRE,
                                         __HIP_MEMORY_SCOPE_AGENT) < 16) {
                    __builtin_amdgcn_s_sleep(1);
                    if (++cnt > (1 << 24)) break;   // safety: never expected
                }
            }
            __syncthreads();
        }

        // ---- S0: stage h, masks, d_{t+1}; hoist elementwise operands ----
        float v_r[4], m_r[4], al_r[4];
#pragma unroll
        for (int i = 0; i < 4; ++i) {
            int e = tid + 256 * i;
            int row = e >> 6;
            int gidx = t * 16384 + (b0 + row) * 64 + (e & 63);
            v_r[i] = values[gidx];
            m_r[i] = b2f(masks[gidx]);
            al_r[i] = b2f(alpha[gidx]);
        }
        if (t == 0) {
            v8s z = {0, 0, 0, 0, 0, 0, 0, 0};
            for (int idx = tid; idx < 1040; idx += 256) ((v8s*)hlds)[idx] = z;
        } else {
            const ushort_t* hcur = bufs[t & 1];
#pragma unroll
            for (int i = 0; i < 4; ++i) {
                int ch = tid + 256 * i;
                int row = ch >> 6, kc = (ch & 63) * 8;
                *(v8s*)(hlds + row * 520 + kc) =
                    *(const v8s*)(hcur + (b0 + row) * 512 + kc);
            }
        }
        if (tid < 128) {
            int row = tid >> 3, c8 = (tid & 7) * 8;
            int tn = (t < 255) ? t + 1 : 255;
            *(v8s*)(inplds + row * 136 + 64 + c8) =
                *(const v8s*)(masks + t * 16384 + (b0 + row) * 64 + c8);
            *(v8s*)(d1b + row * 72 + c8) =
                *(const v8s*)(deltas + tn * 16384 + (b0 + row) * 64 + c8);
        }
        __syncthreads();

        // ---- SA: x_h + gates(Whh) share A-frags (3 chains); gamma tiles ----
        v4f accg0 = {0.f, 0.f, 0.f, 0.f}, accg1 = {0.f, 0.f, 0.f, 0.f};
        {
            v4f accx = {0.f, 0.f, 0.f, 0.f};
#pragma unroll
            for (int kt = 0; kt < 16; ++kt) {
                v8s a = *(const v8s*)(hlds + l15 * 520 + kt * 32 + quad * 8);
                accx = __builtin_amdgcn_mfma_f32_16x16x32_bf16(a, whisF[kt], accx, 0, 0, 0);
                accg0 = __builtin_amdgcn_mfma_f32_16x16x32_bf16(a, whhF[0][kt], accg0, 0, 0, 0);
                accg1 = __builtin_amdgcn_mfma_f32_16x16x32_bf16(a, whhF[1][kt], accg1, 0, 0, 0);
            }
            int ncol = w * 16 + l15;
#pragma unroll
            for (int r = 0; r < 4; ++r) xh_lds[(quad * 4 + r) * 68 + ncol] = accx[r];
        }
        if (w < 2) {
            v4f acc = {0.f, 0.f, 0.f, 0.f};
#pragma unroll
            for (int kt = 0; kt < 2; ++kt) {
                v8s a = *(const v8s*)(d1b + l15 * 72 + kt * 32 + quad * 8);
                acc = __builtin_amdgcn_mfma_f32_16x16x32_bf16(a, wghF[kt], acc, 0, 0, 0);
            }
#pragma unroll
            for (int r = 0; r < 4; ++r) {
                float s = acc[r] + bghv;
                gam[(quad * 4 + r) * 36 + w * 16 + l15] = (s > 0.f) ? __expf(-s) : 1.f;
            }
        }
        __syncthreads();

        // ---- SB: x_c elementwise ----
        float xh_r[4];
#pragma unroll
        for (int i = 0; i < 4; ++i) {
            int e = tid + 256 * i;
            int row = e >> 6, col = e & 63;
            float xh = xh_lds[row * 68 + col] + bhistv;
            float xc = m_r[i] * v_r[i] + (1.f - m_r[i]) * xh;
            xclds[row * 72 + col] = f2b(xc);
            xh_r[i] = xh;
        }
        __syncthreads();

        // ---- SC: z_h MFMA ----
        {
            v4f acc = {0.f, 0.f, 0.f, 0.f};
            int ncol = w * 16 + l15;
#pragma unroll
            for (int kt = 0; kt < 2; ++kt) {
                v8s a = *(const v8s*)(xclds + l15 * 72 + kt * 32 + quad * 8);
                acc = __builtin_amdgcn_mfma_f32_16x16x32_bf16(a, wfF[kt], acc, 0, 0, 0);
            }
#pragma unroll
            for (int r = 0; r < 4; ++r) zh_lds[(quad * 4 + r) * 68 + ncol] = acc[r];
        }
        __syncthreads();

        // ---- SD: c_h, c_c; out write (cb==0) ----
#pragma unroll
        for (int i = 0; i < 4; ++i) {
            int e = tid + 256 * i;
            int row = e >> 6, col = e & 63;
            float zh = zh_lds[row * 68 + col] + bfeatv;
            float ch = al_r[i] * zh + (1.f - al_r[i]) * xh_r[i];
            float cc = m_r[i] * v_r[i] + (1.f - m_r[i]) * ch;
            inplds[row * 136 + col] = f2b(cc);
            if (cb == 0) out[(b0 + row) * 16384 + t * 64 + col] = cc;
        }
        __syncthreads();

        // ---- SE: gates Wih part, finish gate planes ----
#pragma unroll
        for (int nt2 = 0; nt2 < 2; ++nt2) {
            v4f acc = (nt2 == 0) ? accg0 : accg1;
#pragma unroll
            for (int kt = 0; kt < 4; ++kt) {
                v8s a = *(const v8s*)(inplds + l15 * 136 + kt * 32 + quad * 8);
                acc = __builtin_amdgcn_mfma_f32_16x16x32_bf16(a, wihF[nt2][kt], acc, 0, 0, 0);
            }
#pragma unroll
            for (int r = 0; r < 4; ++r)
                gl[w * 576 + (quad * 4 + r) * 36 + nt2 * 16 + l15] = acc[r] + biasv[nt2];
        }
        __syncthreads();

        // ---- SF: LSTM update (cell state in regs) + decayed h write ----
        ushort_t* hnx = bufs[(t + 1) & 1];
#pragma unroll
        for (int i = 0; i < 2; ++i) {
            int e = tid + 256 * i;
            int hcl = e & 31, row = e >> 5;
            float gi = gl[0 * 576 + row * 36 + hcl];
            float gf = gl[1 * 576 + row * 36 + hcl];
            float gg = gl[2 * 576 + row * 36 + hcl];
            float go = gl[3 * 576 + row * 36 + hcl];
            float si = 1.f / (1.f + __expf(-gi));
            float sf = 1.f / (1.f + __expf(-gf));
            float tg = 1.f - 2.f / (__expf(2.f * gg) + 1.f);
            float so = 1.f / (1.f + __expf(-go));
            float cn = sf * c_reg[i] + si * tg;
            c_reg[i] = cn;
            float hn = so * (1.f - 2.f / (__expf(2.f * cn) + 1.f));
            float g = gam[row * 36 + hcl];
            hnx[(b0 + row) * 512 + cb * 32 + hcl] = f2b(hn * g);
        }

        // ---- barrier arrival for step t ----
        __threadfence();
        __syncthreads();
        if (tid == 0)
            __hip_atomic_fetch_add(&bar[rb * 256 + t], 1,
                                   __ATOMIC_RELEASE, __HIP_MEMORY_SCOPE_AGENT);
    }
}

extern "C" void kernel_launch(void* const* d_in, const int* in_sizes, int n_in,
                              void* d_out, int out_size, void* d_ws, size_t ws_size,
                              hipStream_t stream) {
    const float* data  = (const float*)d_in[0];
    const float* Wih   = (const float*)d_in[1];
    const float* Whh   = (const float*)d_in[2];
    const float* bih   = (const float*)d_in[3];
    const float* bhh   = (const float*)d_in[4];
    const float* Wgh   = (const float*)d_in[5];
    const float* bgh   = (const float*)d_in[6];
    const float* Wgx   = (const float*)d_in[7];
    const float* bgx   = (const float*)d_in[8];
    const float* Whist = (const float*)d_in[9];
    const float* bhist = (const float*)d_in[10];
    const float* Wfeat = (const float*)d_in[11];
    const float* bfeat = (const float*)d_in[12];
    const float* Wcomb = (const float*)d_in[13];
    const float* bcomb = (const float*)d_in[14];
    float* out = (float*)d_out;

    char* ws = (char*)d_ws;
    const size_t NTBC = 256UL * 256 * 64;
    float*    values = (float*)ws;    ws += NTBC * 4;
    ushort_t* masksp = (ushort_t*)ws; ws += NTBC * 2;
    ushort_t* deltasp= (ushort_t*)ws; ws += NTBC * 2;
    ushort_t* gammax = (ushort_t*)ws; ws += NTBC * 2;
    ushort_t* alphap = (ushort_t*)ws; ws += NTBC * 2;
    ushort_t* Wih_b  = (ushort_t*)ws; ws += 2048UL * 128 * 2;
    ushort_t* Whh_b  = (ushort_t*)ws; ws += 2048UL * 512 * 2;
    ushort_t* Wgh_b  = (ushort_t*)ws; ws += 512UL * 64 * 2;
    ushort_t* Whist_b = (ushort_t*)ws; ws += 64UL * 512 * 2;
    ushort_t* Wfeat_b = (ushort_t*)ws; ws += 64UL * 64 * 2;
    ushort_t* hA     = (ushort_t*)ws; ws += 256UL * 512 * 2;
    ushort_t* hB     = (ushort_t*)ws; ws += 256UL * 512 * 2;
    int*      bar    = (int*)ws;      ws += 4096UL * 4;

    k_cvt<<<1024, 256, 0, stream>>>(Wih, Wih_b, 2048 * 128);
    k_cvt<<<4096, 256, 0, stream>>>(Whh, Whh_b, 2048 * 512);
    k_cvt<<<128, 256, 0, stream>>>(Wgh, Wgh_b, 512 * 64);
    k_cvt<<<128, 256, 0, stream>>>(Whist, Whist_b, 64 * 512);
    k_cvt<<<16, 256, 0, stream>>>(Wfeat, Wfeat_b, 64 * 64);
    k_zero<<<16, 256, 0, stream>>>(bar, 4096);
    k_pre<<<64, 256, 0, stream>>>(data, Wgx, bgx, values, masksp, deltasp, gammax);
    k_alpha<<<16384, 256, 0, stream>>>(gammax, masksp, Wcomb, bcomb, alphap);

    k_run<<<256, 256, 0, stream>>>(values, masksp, deltasp, alphap,
                                   Wih_b, Whh_b, bih, bhh,
                                   Wgh_b, bgh, Whist_b, bhist,
                                   Wfeat_b, bfeat, hA, hB, bar, out);
}

// Round 5
// 1761.616 us; speedup vs baseline: 3.8212x; 3.8212x over previous
//
#include <hip/hip_runtime.h>

typedef unsigned short ushort_t;
typedef unsigned int uint_t;
typedef unsigned long long ull_t;
typedef short v8s __attribute__((ext_vector_type(8)));
typedef float v4f __attribute__((ext_vector_type(4)));

__device__ __forceinline__ float b2f(ushort_t u) {
    uint_t x = ((uint_t)u) << 16;
    float f;
    __builtin_memcpy(&f, &x, 4);
    return f;
}
__device__ __forceinline__ ushort_t f2b(float f) {
    uint_t x;
    __builtin_memcpy(&x, &f, 4);
    uint_t r = (x + 0x7FFFu + ((x >> 16) & 1u)) >> 16;
    return (ushort_t)r;
}

// ---------------------------------------------------------------------------
__global__ void k_cvt(const float* __restrict__ src, ushort_t* __restrict__ dst, int n) {
    int i = blockIdx.x * 256 + threadIdx.x;
    if (i < n) dst[i] = f2b(src[i]);
}

__global__ void k_zero(int* __restrict__ p, int n) {
    int i = blockIdx.x * 256 + threadIdx.x;
    if (i < n) p[i] = 0;
}

// ---------------------------------------------------------------------------
// K1: per-(b,c) scan over t: values(f32), masks/deltas/gamma_x (bf16). [T,B,C]
// ---------------------------------------------------------------------------
__global__ void k_pre(const float* __restrict__ data,
                      const float* __restrict__ Wgx,
                      const float* __restrict__ bgx,
                      float* __restrict__ values, ushort_t* __restrict__ masks,
                      ushort_t* __restrict__ deltas, ushort_t* __restrict__ gammax) {
    int id = blockIdx.x * 256 + threadIdx.x;   // 0..16383 = b*64+c
    int b = id >> 6, c = id & 63;
    float wd = Wgx[c * 64 + c];
    float bg = bgx[c];
    float d_prev = 0.f, m_prev = 0.f;
    for (int t = 0; t < 256; ++t) {
        float x = data[b * 16384 + t * 64 + c];
        bool nan = (x != x);
        float m = nan ? 0.f : 1.f;
        float v = nan ? 0.f : x;
        float d;
        if (t == 0) d = 0.f;
        else if (t == 1) d = 1.f;
        else d = (m_prev == 1.f) ? 1.f : d_prev + 1.f;
        float s = d * wd + bg;
        float gx = (s > 0.f) ? __expf(-s) : 1.f;
        int o = t * 16384 + id;
        values[o] = v;
        masks[o]  = f2b(m);
        deltas[o] = f2b(d);
        gammax[o] = f2b(gx);
        m_prev = m; d_prev = d;
    }
}

// ---------------------------------------------------------------------------
// K2: alpha[t,b,i]
// ---------------------------------------------------------------------------
__global__ void k_alpha(const ushort_t* __restrict__ gammax,
                        const ushort_t* __restrict__ masks,
                        const float* __restrict__ Wcomb,
                        const float* __restrict__ bcomb,
                        ushort_t* __restrict__ alpha) {
    int id = blockIdx.x * 256 + threadIdx.x;
    int i = id & 63;
    int tb = id >> 6;
    const ushort_t* gx = gammax + tb * 64;
    const ushort_t* mk = masks + tb * 64;
    const float* w0 = Wcomb + i * 128;
    float acc = bcomb[i];
#pragma unroll
    for (int j0 = 0; j0 < 64; j0 += 8) {
        v8s g = *(const v8s*)(gx + j0);
        v8s m = *(const v8s*)(mk + j0);
#pragma unroll
        for (int j = 0; j < 8; ++j) {
            acc += b2f((ushort_t)g[j]) * w0[j0 + j];
            acc += b2f((ushort_t)m[j]) * w0[64 + j0 + j];
        }
    }
    alpha[id] = f2b(acc);
}

// ---------------------------------------------------------------------------
// Persistent step kernel, fence-free sync:
//  - h crosses workgroups only via RELAXED agent-scope atomics (coherence
//    point), so no L2 writeback/invalidate is ever required.
//  - producer: s_waitcnt(own stores) -> syncthreads -> relaxed flag store.
//  - consumer: relaxed poll of the 16 group flags (wave 0), syncthreads,
//    then relaxed atomic h loads (in-order issue => cannot start early).
// ---------------------------------------------------------------------------
__global__ __launch_bounds__(256, 1) void k_run(
    const float* __restrict__ values, const ushort_t* __restrict__ masks,
    const ushort_t* __restrict__ deltas, const ushort_t* __restrict__ alpha,
    const ushort_t* __restrict__ Wih, const ushort_t* __restrict__ Whh,
    const float* __restrict__ bih, const float* __restrict__ bhh,
    const ushort_t* __restrict__ Wgh, const float* __restrict__ bgh,
    const ushort_t* __restrict__ Whist, const float* __restrict__ bhist,
    const ushort_t* __restrict__ Wfeat, const float* __restrict__ bfeat,
    ushort_t* __restrict__ hA, ushort_t* __restrict__ hB,
    int* __restrict__ flags, float* __restrict__ out) {
    __shared__ __attribute__((aligned(16))) ushort_t hlds[16 * 520];   // h_dec bf16
    __shared__ __attribute__((aligned(16))) ushort_t inplds[16 * 136]; // [c_c | m]
    __shared__ __attribute__((aligned(16))) ushort_t xclds[16 * 72];   // x_c bf16
    __shared__ __attribute__((aligned(16))) ushort_t d1b[16 * 72];     // delta_{t+1} bf16
    __shared__ __attribute__((aligned(16))) float xh_lds[16 * 68];
    __shared__ __attribute__((aligned(16))) float zh_lds[16 * 68];
    __shared__ __attribute__((aligned(16))) float gl[4 * 16 * 36];     // gate planes
    __shared__ __attribute__((aligned(16))) float gam[16 * 36];        // gamma_h tile

    int tid = threadIdx.x;
    int w = tid >> 6;
    int lane = tid & 63;
    int l15 = lane & 15, quad = lane >> 4;
    int wg = blockIdx.x;
    int rb = wg & 15, cb = wg >> 4;
    int b0 = rb * 16;

    // ---- one-time: persistent weight fragments in VGPRs ----
    v8s whhF[2][16], wihF[2][4], whisF[16], wfF[2], wghF[2] = {};
    float biasv[2];
#pragma unroll
    for (int nt2 = 0; nt2 < 2; ++nt2) {
        int hc = cb * 32 + nt2 * 16 + l15;
        int rW = w * 512 + hc;
        const ushort_t* whrow = Whh + rW * 512;
        const ushort_t* wirow = Wih + rW * 128;
#pragma unroll
        for (int kt = 0; kt < 16; ++kt)
            whhF[nt2][kt] = *(const v8s*)(whrow + kt * 32 + quad * 8);
#pragma unroll
        for (int kt = 0; kt < 4; ++kt)
            wihF[nt2][kt] = *(const v8s*)(wirow + kt * 32 + quad * 8);
        biasv[nt2] = bih[rW] + bhh[rW];
    }
    {
        int ncol = w * 16 + l15;
        const ushort_t* hrow = Whist + ncol * 512;
#pragma unroll
        for (int kt = 0; kt < 16; ++kt)
            whisF[kt] = *(const v8s*)(hrow + kt * 32 + quad * 8);
        const ushort_t* frow = Wfeat + ncol * 64;
#pragma unroll
        for (int kt = 0; kt < 2; ++kt) {
            int k0 = kt * 32 + quad * 8;
            v8s bb = *(const v8s*)(frow + k0);
#pragma unroll
            for (int j = 0; j < 8; ++j)
                if (k0 + j == ncol) bb[j] = 0;   // zero diagonal
            wfF[kt] = bb;
        }
    }
    float bghv = 0.f;
    if (w < 2) {
        int gcol = cb * 32 + w * 16 + l15;
        const ushort_t* grow = Wgh + gcol * 64;
#pragma unroll
        for (int kt = 0; kt < 2; ++kt)
            wghF[kt] = *(const v8s*)(grow + kt * 32 + quad * 8);
        bghv = bgh[gcol];
    }
    float bhistv = bhist[tid & 63];
    float bfeatv = bfeat[tid & 63];

    // SF ownership: threads 0..127 own (row = tid>>3, cols c4g..c4g+3)
    int sf_row = tid >> 3, sf_c4 = (tid & 7) * 4;
    float c_reg4[4] = {0.f, 0.f, 0.f, 0.f};

    ushort_t* bufs[2] = {hA, hB};

    for (int t = 0; t < 256; ++t) {
        // ---- P: prefetch t-indexed inputs into regs (race-free arrays) ----
        float v_r[4], m_r[4], al_r[4];
#pragma unroll
        for (int i = 0; i < 4; ++i) {
            int e = tid + 256 * i;
            int row = e >> 6;
            int gidx = t * 16384 + (b0 + row) * 64 + (e & 63);
            v_r[i] = values[gidx];
            m_r[i] = b2f(masks[gidx]);
            al_r[i] = b2f(alpha[gidx]);
        }
        v8s mreg = {}, dreg = {};
        if (tid < 128) {
            int row = tid >> 3, c8 = (tid & 7) * 8;
            int tn = (t < 255) ? t + 1 : 255;
            mreg = *(const v8s*)(masks + t * 16384 + (b0 + row) * 64 + c8);
            dreg = *(const v8s*)(deltas + tn * 16384 + (b0 + row) * 64 + c8);
        }

        // ---- W: wait for all 16 producers of h_t (relaxed poll, wave 0) ----
        if (t > 0) {
            if (tid < 64) {
                if (lane < 16) {
                    const int* fp = flags + (lane * 16 + rb) * 16;
                    int cnt = 0;
                    while (__hip_atomic_load(fp, __ATOMIC_RELAXED,
                                             __HIP_MEMORY_SCOPE_AGENT) < t) {
                        __builtin_amdgcn_s_sleep(2);
                        if (++cnt > (1 << 24)) break;   // safety
                    }
                }
            }
            __syncthreads();
        }

        // ---- S0: stage h (atomic bypass loads), masks, d_{t+1} ----
        if (t == 0) {
            v8s z = {0, 0, 0, 0, 0, 0, 0, 0};
            for (int idx = tid; idx < 1040; idx += 256) ((v8s*)hlds)[idx] = z;
        } else {
            const ushort_t* hcur = bufs[t & 1];
#pragma unroll
            for (int i = 0; i < 8; ++i) {
                int c = tid + 256 * i;              // 2048 chunks of 4 bf16
                int row = c >> 7, c4 = (c & 127) * 4;
                ull_t hv = __hip_atomic_load(
                    (const ull_t*)(hcur + (b0 + row) * 512 + c4),
                    __ATOMIC_RELAXED, __HIP_MEMORY_SCOPE_AGENT);
                *(ull_t*)(hlds + row * 520 + c4) = hv;
            }
        }
        if (tid < 128) {
            int row = tid >> 3, c8 = (tid & 7) * 8;
            *(v8s*)(inplds + row * 136 + 64 + c8) = mreg;
            *(v8s*)(d1b + row * 72 + c8) = dreg;
        }
        __syncthreads();

        // ---- SA: x_h + gates(Whh) share A-frags (3 chains); gamma tile ----
        v4f accg0 = {0.f, 0.f, 0.f, 0.f}, accg1 = {0.f, 0.f, 0.f, 0.f};
        {
            v4f accx = {0.f, 0.f, 0.f, 0.f};
#pragma unroll
            for (int kt = 0; kt < 16; ++kt) {
                v8s a = *(const v8s*)(hlds + l15 * 520 + kt * 32 + quad * 8);
                accx = __builtin_amdgcn_mfma_f32_16x16x32_bf16(a, whisF[kt], accx, 0, 0, 0);
                accg0 = __builtin_amdgcn_mfma_f32_16x16x32_bf16(a, whhF[0][kt], accg0, 0, 0, 0);
                accg1 = __builtin_amdgcn_mfma_f32_16x16x32_bf16(a, whhF[1][kt], accg1, 0, 0, 0);
            }
            int ncol = w * 16 + l15;
#pragma unroll
            for (int r = 0; r < 4; ++r) xh_lds[(quad * 4 + r) * 68 + ncol] = accx[r];
        }
        if (w < 2) {
            v4f acc = {0.f, 0.f, 0.f, 0.f};
#pragma unroll
            for (int kt = 0; kt < 2; ++kt) {
                v8s a = *(const v8s*)(d1b + l15 * 72 + kt * 32 + quad * 8);
                acc = __builtin_amdgcn_mfma_f32_16x16x32_bf16(a, wghF[kt], acc, 0, 0, 0);
            }
#pragma unroll
            for (int r = 0; r < 4; ++r) {
                float s = acc[r] + bghv;
                gam[(quad * 4 + r) * 36 + w * 16 + l15] = (s > 0.f) ? __expf(-s) : 1.f;
            }
        }
        __syncthreads();

        // ---- SB: x_c elementwise ----
        float xh_r[4];
#pragma unroll
        for (int i = 0; i < 4; ++i) {
            int e = tid + 256 * i;
            int row = e >> 6, col = e & 63;
            float xh = xh_lds[row * 68 + col] + bhistv;
            float xc = m_r[i] * v_r[i] + (1.f - m_r[i]) * xh;
            xclds[row * 72 + col] = f2b(xc);
            xh_r[i] = xh;
        }
        __syncthreads();

        // ---- SC: z_h MFMA ----
        {
            v4f acc = {0.f, 0.f, 0.f, 0.f};
            int ncol = w * 16 + l15;
#pragma unroll
            for (int kt = 0; kt < 2; ++kt) {
                v8s a = *(const v8s*)(xclds + l15 * 72 + kt * 32 + quad * 8);
                acc = __builtin_amdgcn_mfma_f32_16x16x32_bf16(a, wfF[kt], acc, 0, 0, 0);
            }
#pragma unroll
            for (int r = 0; r < 4; ++r) zh_lds[(quad * 4 + r) * 68 + ncol] = acc[r];
        }
        __syncthreads();

        // ---- SD: c_h, c_c; out write (cb==0) ----
#pragma unroll
        for (int i = 0; i < 4; ++i) {
            int e = tid + 256 * i;
            int row = e >> 6, col = e & 63;
            float zh = zh_lds[row * 68 + col] + bfeatv;
            float ch = al_r[i] * zh + (1.f - al_r[i]) * xh_r[i];
            float cc = m_r[i] * v_r[i] + (1.f - m_r[i]) * ch;
            inplds[row * 136 + col] = f2b(cc);
            if (cb == 0) out[(b0 + row) * 16384 + t * 64 + col] = cc;
        }
        __syncthreads();

        // ---- SE: gates Wih part, finish gate planes ----
#pragma unroll
        for (int nt2 = 0; nt2 < 2; ++nt2) {
            v4f acc = (nt2 == 0) ? accg0 : accg1;
#pragma unroll
            for (int kt = 0; kt < 4; ++kt) {
                v8s a = *(const v8s*)(inplds + l15 * 136 + kt * 32 + quad * 8);
                acc = __builtin_amdgcn_mfma_f32_16x16x32_bf16(a, wihF[nt2][kt], acc, 0, 0, 0);
            }
#pragma unroll
            for (int r = 0; r < 4; ++r)
                gl[w * 576 + (quad * 4 + r) * 36 + nt2 * 16 + l15] = acc[r] + biasv[nt2];
        }
        __syncthreads();

        // ---- SF: LSTM update (cell state in regs, 4 cols/thread) ----
        if (tid < 128) {
            ull_t outv = 0;
#pragma unroll
            for (int j = 0; j < 4; ++j) {
                int hcl = sf_c4 + j;
                float gi = gl[0 * 576 + sf_row * 36 + hcl];
                float gf = gl[1 * 576 + sf_row * 36 + hcl];
                float gg = gl[2 * 576 + sf_row * 36 + hcl];
                float go = gl[3 * 576 + sf_row * 36 + hcl];
                float si = 1.f / (1.f + __expf(-gi));
                float sf = 1.f / (1.f + __expf(-gf));
                float tg = 1.f - 2.f / (__expf(2.f * gg) + 1.f);
                float so = 1.f / (1.f + __expf(-go));
                float cn = sf * c_reg4[j] + si * tg;
                c_reg4[j] = cn;
                float hn = so * (1.f - 2.f / (__expf(2.f * cn) + 1.f));
                float g = gam[sf_row * 36 + hcl];
                outv |= (ull_t)f2b(hn * g) << (16 * j);
            }
            if (t < 255) {
                ushort_t* hnx = bufs[(t + 1) & 1];
                __hip_atomic_store(
                    (ull_t*)(hnx + (b0 + sf_row) * 512 + cb * 32 + sf_c4),
                    outv, __ATOMIC_RELAXED, __HIP_MEMORY_SCOPE_AGENT);
            }
        }

        // ---- signal: drain own stores, then relaxed flag store ----
        if (t < 255) {
            __builtin_amdgcn_s_waitcnt(0);   // vmcnt/lgkm/exp = 0
            __syncthreads();
            if (tid == 0)
                __hip_atomic_store(&flags[wg * 16], t + 1,
                                   __ATOMIC_RELAXED, __HIP_MEMORY_SCOPE_AGENT);
        }
    }
}

extern "C" void kernel_launch(void* const* d_in, const int* in_sizes, int n_in,
                              void* d_out, int out_size, void* d_ws, size_t ws_size,
                              hipStream_t stream) {
    const float* data  = (const float*)d_in[0];
    const float* Wih   = (const float*)d_in[1];
    const float* Whh   = (const float*)d_in[2];
    const float* bih   = (const float*)d_in[3];
    const float* bhh   = (const float*)d_in[4];
    const float* Wgh   = (const float*)d_in[5];
    const float* bgh   = (const float*)d_in[6];
    const float* Wgx   = (const float*)d_in[7];
    const float* bgx   = (const float*)d_in[8];
    const float* Whist = (const float*)d_in[9];
    const float* bhist = (const float*)d_in[10];
    const float* Wfeat = (const float*)d_in[11];
    const float* bfeat = (const float*)d_in[12];
    const float* Wcomb = (const float*)d_in[13];
    const float* bcomb = (const float*)d_in[14];
    float* out = (float*)d_out;

    char* ws = (char*)d_ws;
    const size_t NTBC = 256UL * 256 * 64;
    float*    values = (float*)ws;    ws += NTBC * 4;
    ushort_t* masksp = (ushort_t*)ws; ws += NTBC * 2;
    ushort_t* deltasp= (ushort_t*)ws; ws += NTBC * 2;
    ushort_t* gammax = (ushort_t*)ws; ws += NTBC * 2;
    ushort_t* alphap = (ushort_t*)ws; ws += NTBC * 2;
    ushort_t* Wih_b  = (ushort_t*)ws; ws += 2048UL * 128 * 2;
    ushort_t* Whh_b  = (ushort_t*)ws; ws += 2048UL * 512 * 2;
    ushort_t* Wgh_b  = (ushort_t*)ws; ws += 512UL * 64 * 2;
    ushort_t* Whist_b = (ushort_t*)ws; ws += 64UL * 512 * 2;
    ushort_t* Wfeat_b = (ushort_t*)ws; ws += 64UL * 64 * 2;
    ushort_t* hA     = (ushort_t*)ws; ws += 256UL * 512 * 2;
    ushort_t* hB     = (ushort_t*)ws; ws += 256UL * 512 * 2;
    int*      flags  = (int*)ws;      ws += 4096UL * 4;

    k_cvt<<<1024, 256, 0, stream>>>(Wih, Wih_b, 2048 * 128);
    k_cvt<<<4096, 256, 0, stream>>>(Whh, Whh_b, 2048 * 512);
    k_cvt<<<128, 256, 0, stream>>>(Wgh, Wgh_b, 512 * 64);
    k_cvt<<<128, 256, 0, stream>>>(Whist, Whist_b, 64 * 512);
    k_cvt<<<16, 256, 0, stream>>>(Wfeat, Wfeat_b, 64 * 64);
    k_zero<<<16, 256, 0, stream>>>(flags, 4096);
    k_pre<<<64, 256, 0, stream>>>(data, Wgx, bgx, values, masksp, deltasp, gammax);
    k_alpha<<<16384, 256, 0, stream>>>(gammax, masksp, Wcomb, bcomb, alphap);

    k_run<<<256, 256, 0, stream>>>(values, masksp, deltasp, alphap,
                                   Wih_b, Whh_b, bih, bhh,
                                   Wgh_b, bgh, Whist_b, bhist,
                                   Wfeat_b, bfeat, hA, hB, flags, out);
}

// Round 8
// 967.011 us; speedup vs baseline: 6.9612x; 1.8217x over previous
//
#include <hip/hip_runtime.h>

typedef unsigned short ushort_t;
typedef unsigned int uint_t;
typedef unsigned long long ull_t;
typedef short v8s __attribute__((ext_vector_type(8)));
typedef float v4f __attribute__((ext_vector_type(4)));

__device__ __forceinline__ float b2f(ushort_t u) {
    uint_t x = ((uint_t)u) << 16;
    float f;
    __builtin_memcpy(&f, &x, 4);
    return f;
}
__device__ __forceinline__ ushort_t f2b(float f) {
    uint_t x;
    __builtin_memcpy(&x, &f, 4);
    uint_t r = (x + 0x7FFFu + ((x >> 16) & 1u)) >> 16;
    return (ushort_t)r;
}

// ---------------------------------------------------------------------------
// k_setup: zero 8-slot h ring (64 blocks) + weight fp32->bf16 conversions.
// grid = 64 + 1024 + 4096 + 128 + 128 + 16 = 5456 blocks of 256.
// ---------------------------------------------------------------------------
__global__ __launch_bounds__(256) void k_setup(
    const float* __restrict__ Wih, const float* __restrict__ Whh,
    const float* __restrict__ Wgh, const float* __restrict__ Whist,
    const float* __restrict__ Wfeat,
    ushort_t* __restrict__ Wih_b, ushort_t* __restrict__ Whh_b,
    ushort_t* __restrict__ Wgh_b, ushort_t* __restrict__ Whist_b,
    ushort_t* __restrict__ Wfeat_b, ull_t* __restrict__ hbufs) {
    int bid = blockIdx.x, tid = threadIdx.x;
    if (bid < 64) {   // zero 8 slots x 131072 u16 = 262144 ull
        ull_t* p = hbufs + (size_t)bid * 4096 + tid;
#pragma unroll
        for (int i = 0; i < 16; ++i) p[i * 256] = 0;
        return;
    }
    bid -= 64;
    const float* src; ushort_t* dst; int n;
    if (bid < 1024)      { src = Wih;   dst = Wih_b;   n = 262144; }
    else if (bid < 5120) { bid -= 1024; src = Whh;   dst = Whh_b;   n = 1048576; }
    else if (bid < 5248) { bid -= 5120; src = Wgh;   dst = Wgh_b;   n = 32768; }
    else if (bid < 5376) { bid -= 5248; src = Whist; dst = Whist_b; n = 32768; }
    else                 { bid -= 5376; src = Wfeat; dst = Wfeat_b; n = 4096; }
    int i = bid * 256 + tid;
    if (i < n) dst[i] = f2b(src[i]);
}

// ---------------------------------------------------------------------------
// k_pre: 512 blocks; each block = 32 (b,c) pairs x 8 threads over T chunks.
// delta[t] = t - L(t), L(t) = last t' in [1,t-1] with m[t']=1 (else 0).
// ---------------------------------------------------------------------------
__global__ __launch_bounds__(256) void k_pre(
    const float* __restrict__ data, const float* __restrict__ Wgx,
    const float* __restrict__ bgx,
    ushort_t* __restrict__ values, ushort_t* __restrict__ masks,
    ushort_t* __restrict__ deltas, ushort_t* __restrict__ gammax) {
    __shared__ int lastl[32][9];
    int tid = threadIdx.x;
    int j = tid >> 5, p = tid & 31;
    int pid = blockIdx.x * 32 + p;      // 0..16383
    int b = pid >> 6, c = pid & 63;
    float wd = Wgx[c * 64 + c], bg = bgx[c];
    int t0 = j * 32;
    const float* dp = data + (size_t)b * 16384 + c;
    float v[32]; uint_t bits = 0;
#pragma unroll
    for (int s = 0; s < 32; ++s) {
        float x = dp[(t0 + s) * 64];
        bool obs = (x == x);
        v[s] = obs ? x : 0.f;
        bits |= obs ? (1u << s) : 0u;
    }
    uint_t vb = bits;
    if (j == 0) vb &= ~1u;              // t=0 never counts as observation
    int lastloc = 0;
    if (vb) lastloc = t0 + (31 - __clz(vb));
    lastl[p][j] = lastloc;
    __syncthreads();
    int L = 0;
    for (int jj = 0; jj < j; ++jj) L = max(L, lastl[p][jj]);
#pragma unroll
    for (int s = 0; s < 32; ++s) {
        int t = t0 + s;
        float m = ((bits >> s) & 1) ? 1.f : 0.f;
        float d = (t == 0) ? 0.f : (float)(t - L);
        float sg = d * wd + bg;
        float gx = (sg > 0.f) ? __expf(-sg) : 1.f;
        size_t o = (size_t)t * 16384 + pid;
        values[o] = f2b(v[s]); masks[o] = f2b(m);
        deltas[o] = f2b(d);    gammax[o] = f2b(gx);
        if (((bits >> s) & 1) && t >= 1) L = t;
    }
}

// ---------------------------------------------------------------------------
// k_alpha: 4096 blocks x 16 (t,b) rows (T*B = 65536 rows total!).
// Wcomb staged to LDS once per block.
// ---------------------------------------------------------------------------
__global__ __launch_bounds__(256) void k_alpha(
    const ushort_t* __restrict__ gammax, const ushort_t* __restrict__ masks,
    const float* __restrict__ Wcomb, const float* __restrict__ bcomb,
    ushort_t* __restrict__ alpha) {
    __shared__ __attribute__((aligned(16))) ushort_t wl[64 * 136];
    __shared__ __attribute__((aligned(16))) ushort_t al[16 * 136];
    int tid = threadIdx.x;
    for (int idx = tid; idx < 8192; idx += 256) {
        int r = idx >> 7, kcol = idx & 127;
        wl[r * 136 + kcol] = f2b(Wcomb[idx]);
    }
    int tb0 = blockIdx.x * 16;
    for (int idx = tid; idx < 2048; idx += 256) {
        int r = idx >> 7, kcol = idx & 127;
        al[r * 136 + kcol] = (kcol < 64)
            ? gammax[(size_t)(tb0 + r) * 64 + kcol]
            : masks[(size_t)(tb0 + r) * 64 + (kcol - 64)];
    }
    __syncthreads();
    int i = tid & 63, rg = (tid >> 6) * 4;
    float bc = bcomb[i];
    float acc[4] = {bc, bc, bc, bc};
#pragma unroll
    for (int k8 = 0; k8 < 16; ++k8) {
        v8s w8 = *(const v8s*)(wl + i * 136 + k8 * 8);
#pragma unroll
        for (int rr = 0; rr < 4; ++rr) {
            v8s a8 = *(const v8s*)(al + (rg + rr) * 136 + k8 * 8);
#pragma unroll
            for (int q = 0; q < 8; ++q)
                acc[rr] += b2f((ushort_t)a8[q]) * b2f((ushort_t)w8[q]);
        }
    }
#pragma unroll
    for (int rr = 0; rr < 4; ++rr)
        alpha[(size_t)(tb0 + rg + rr) * 64 + i] = f2b(acc[rr]);
}

// ---------------------------------------------------------------------------
// k_run: persistent, 8-slot h ring, data-polling sync (bf16+1 encoding),
// producer pre-zero of slot (t+4)%8 (safe: intra-group drift <= 1 step and
// every __syncthreads drains vmcnt, so zeros are globally visible >=2 steps
// before any producer can rewrite or any consumer can poll that slot).
// ---------------------------------------------------------------------------
__global__ __launch_bounds__(256, 1) void k_run(
    const ushort_t* __restrict__ values, const ushort_t* __restrict__ masks,
    const ushort_t* __restrict__ deltas, const ushort_t* __restrict__ alpha,
    const ushort_t* __restrict__ Wih, const ushort_t* __restrict__ Whh,
    const float* __restrict__ bih, const float* __restrict__ bhh,
    const ushort_t* __restrict__ Wgh, const float* __restrict__ bgh,
    const ushort_t* __restrict__ Whist, const float* __restrict__ bhist,
    const ushort_t* __restrict__ Wfeat, const float* __restrict__ bfeat,
    ushort_t* __restrict__ hbufs, float* __restrict__ out) {
    __shared__ __attribute__((aligned(16))) ushort_t hlds[16 * 520];
    __shared__ __attribute__((aligned(16))) ushort_t inplds[16 * 136];
    __shared__ __attribute__((aligned(16))) ushort_t xclds[16 * 72];
    __shared__ __attribute__((aligned(16))) ushort_t d1b[16 * 72];
    __shared__ __attribute__((aligned(16))) float gl[4 * 16 * 36];
    __shared__ __attribute__((aligned(16))) float gam[16 * 36];

    int tid = threadIdx.x;
    int w = tid >> 6;
    int lane = tid & 63;
    int l15 = lane & 15, quad = lane >> 4;
    int wg = blockIdx.x;
    int rb = wg & 15, cb = wg >> 4;
    int b0 = rb * 16;

    // ---- persistent weight fragments ----
    v8s whhF[2][16], wihF[2][4], whisF[16], wfF[2], wghF[2] = {};
    float biasv[2];
#pragma unroll
    for (int nt2 = 0; nt2 < 2; ++nt2) {
        int hc = cb * 32 + nt2 * 16 + l15;
        int rW = w * 512 + hc;
        const ushort_t* whrow = Whh + (size_t)rW * 512;
        const ushort_t* wirow = Wih + (size_t)rW * 128;
#pragma unroll
        for (int kt = 0; kt < 16; ++kt)
            whhF[nt2][kt] = *(const v8s*)(whrow + kt * 32 + quad * 8);
#pragma unroll
        for (int kt = 0; kt < 4; ++kt)
            wihF[nt2][kt] = *(const v8s*)(wirow + kt * 32 + quad * 8);
        biasv[nt2] = bih[rW] + bhh[rW];
    }
    int colC = w * 16 + l15;
    {
        const ushort_t* hrow = Whist + (size_t)colC * 512;
#pragma unroll
        for (int kt = 0; kt < 16; ++kt)
            whisF[kt] = *(const v8s*)(hrow + kt * 32 + quad * 8);
        const ushort_t* frow = Wfeat + colC * 64;
#pragma unroll
        for (int kt = 0; kt < 2; ++kt) {
            int k0 = kt * 32 + quad * 8;
            v8s bb = *(const v8s*)(frow + k0);
#pragma unroll
            for (int j = 0; j < 8; ++j)
                if (k0 + j == colC) bb[j] = 0;   // zero diagonal
            wfF[kt] = bb;
        }
    }
    float bghv = 0.f;
    if (w < 2) {
        int gcol = cb * 32 + w * 16 + l15;
        const ushort_t* grow = Wgh + gcol * 64;
#pragma unroll
        for (int kt = 0; kt < 2; ++kt)
            wghF[kt] = *(const v8s*)(grow + kt * 32 + quad * 8);
        bghv = bgh[gcol];
    }
    float bhistv = bhist[colC];
    float bfeatv = bfeat[colC];

    int sf_row = tid >> 3, sf_c4 = (tid & 7) * 4;
    float c_reg4[4] = {0.f, 0.f, 0.f, 0.f};

    for (int t = 0; t < 256; ++t) {
        // ---- P: prefetch (no cross-wg deps) ----
        float v4r[4], m4r[4], a4r[4];
#pragma unroll
        for (int r = 0; r < 4; ++r) {
            int row = quad * 4 + r;
            size_t g = (size_t)t * 16384 + (b0 + row) * 64 + colC;
            v4r[r] = b2f(values[g]);
            m4r[r] = b2f(masks[g]);
            a4r[r] = b2f(alpha[g]);
        }
        v8s mreg = {}, dreg = {};
        if (tid < 128) {
            int row = tid >> 3, c8 = (tid & 7) * 8;
            int tn = (t < 255) ? t + 1 : 255;
            mreg = *(const v8s*)(masks + (size_t)t * 16384 + (b0 + row) * 64 + c8);
            dreg = *(const v8s*)(deltas + (size_t)tn * 16384 + (b0 + row) * 64 + c8);
        }

        // ---- S0: poll h(t) data directly; decode; stage LDS ----
        if (t == 0) {
            v8s z = {0, 0, 0, 0, 0, 0, 0, 0};
            for (int idx = tid; idx < 1040; idx += 256) ((v8s*)hlds)[idx] = z;
        } else {
            const ushort_t* hb = hbufs + (size_t)(t & 7) * 131072;
            const ull_t* hp[8];
            ull_t hv[8];
#pragma unroll
            for (int i = 0; i < 8; ++i) {
                int c = tid + 256 * i;
                int row = c >> 7, c4 = (c & 127) * 4;
                hp[i] = (const ull_t*)(hb + (b0 + row) * 512 + c4);
                hv[i] = __hip_atomic_load(hp[i], __ATOMIC_RELAXED,
                                          __HIP_MEMORY_SCOPE_AGENT);
            }
            int guard = 0;
            while (true) {
                bool any = false;
#pragma unroll
                for (int i = 0; i < 8; ++i) any |= (hv[i] == 0);
                if (!any || ++guard > (1 << 20)) break;
                __builtin_amdgcn_s_sleep(1);
#pragma unroll
                for (int i = 0; i < 8; ++i)
                    if (hv[i] == 0)
                        hv[i] = __hip_atomic_load(hp[i], __ATOMIC_RELAXED,
                                                  __HIP_MEMORY_SCOPE_AGENT);
            }
#pragma unroll
            for (int i = 0; i < 8; ++i) {
                int c = tid + 256 * i;
                int row = c >> 7, c4 = (c & 127) * 4;
                *(ull_t*)(hlds + row * 520 + c4) =
                    hv[i] - 0x0001000100010001ULL;   // decode bf16+1
            }
        }
        if (tid < 128) {
            int row = tid >> 3, c8 = (tid & 7) * 8;
            *(v8s*)(inplds + row * 136 + 64 + c8) = mreg;
            *(v8s*)(d1b + row * 72 + c8) = dreg;
        }
        __syncthreads();

        // ---- SA: xh + 2 gate chains share A-frags; gamma tile; xc epilogue --
        v4f accx = {0.f, 0.f, 0.f, 0.f};
        v4f accg0 = {0.f, 0.f, 0.f, 0.f}, accg1 = {0.f, 0.f, 0.f, 0.f};
#pragma unroll
        for (int kt = 0; kt < 16; ++kt) {
            v8s a = *(const v8s*)(hlds + l15 * 520 + kt * 32 + quad * 8);
            accx = __builtin_amdgcn_mfma_f32_16x16x32_bf16(a, whisF[kt], accx, 0, 0, 0);
            accg0 = __builtin_amdgcn_mfma_f32_16x16x32_bf16(a, whhF[0][kt], accg0, 0, 0, 0);
            accg1 = __builtin_amdgcn_mfma_f32_16x16x32_bf16(a, whhF[1][kt], accg1, 0, 0, 0);
        }
        if (w < 2) {
            v4f acc = {0.f, 0.f, 0.f, 0.f};
#pragma unroll
            for (int kt = 0; kt < 2; ++kt) {
                v8s a = *(const v8s*)(d1b + l15 * 72 + kt * 32 + quad * 8);
                acc = __builtin_amdgcn_mfma_f32_16x16x32_bf16(a, wghF[kt], acc, 0, 0, 0);
            }
#pragma unroll
            for (int r = 0; r < 4; ++r) {
                float s = acc[r] + bghv;
                gam[(quad * 4 + r) * 36 + w * 16 + l15] = (s > 0.f) ? __expf(-s) : 1.f;
            }
        }
        float xh4[4];
#pragma unroll
        for (int r = 0; r < 4; ++r) {
            float xh = accx[r] + bhistv;
            float xc = m4r[r] * v4r[r] + (1.f - m4r[r]) * xh;
            xclds[(quad * 4 + r) * 72 + colC] = f2b(xc);
            xh4[r] = xh;
        }
        __syncthreads();

        // ---- SC: z_h MFMA; c_h/c_c epilogue in C-layout; out store ----
        {
            v4f accz = {0.f, 0.f, 0.f, 0.f};
#pragma unroll
            for (int kt = 0; kt < 2; ++kt) {
                v8s a = *(const v8s*)(xclds + l15 * 72 + kt * 32 + quad * 8);
                accz = __builtin_amdgcn_mfma_f32_16x16x32_bf16(a, wfF[kt], accz, 0, 0, 0);
            }
#pragma unroll
            for (int r = 0; r < 4; ++r) {
                float zh = accz[r] + bfeatv;
                float ch = a4r[r] * zh + (1.f - a4r[r]) * xh4[r];
                float cc = m4r[r] * v4r[r] + (1.f - m4r[r]) * ch;
                int row = quad * 4 + r;
                inplds[row * 136 + colC] = f2b(cc);
                if (cb == 0)
                    out[(size_t)(b0 + row) * 16384 + t * 64 + colC] = cc;
            }
        }
        __syncthreads();

        // ---- SE: gates Wih part; gate planes ----
#pragma unroll
        for (int nt2 = 0; nt2 < 2; ++nt2) {
            v4f acc = (nt2 == 0) ? accg0 : accg1;
#pragma unroll
            for (int kt = 0; kt < 4; ++kt) {
                v8s a = *(const v8s*)(inplds + l15 * 136 + kt * 32 + quad * 8);
                acc = __builtin_amdgcn_mfma_f32_16x16x32_bf16(a, wihF[nt2][kt], acc, 0, 0, 0);
            }
#pragma unroll
            for (int r = 0; r < 4; ++r)
                gl[w * 576 + (quad * 4 + r) * 36 + nt2 * 16 + l15] = acc[r] + biasv[nt2];
        }
        __syncthreads();

        // ---- SF: LSTM + decay + encoded h store; pre-zero slot (t+4)%8 ----
        if (tid < 128) {
            ull_t outv = 0;
#pragma unroll
            for (int j = 0; j < 4; ++j) {
                int hcl = sf_c4 + j;
                float gi = gl[0 * 576 + sf_row * 36 + hcl];
                float gf = gl[1 * 576 + sf_row * 36 + hcl];
                float gg = gl[2 * 576 + sf_row * 36 + hcl];
                float go = gl[3 * 576 + sf_row * 36 + hcl];
                float si = 1.f / (1.f + __expf(-gi));
                float sf = 1.f / (1.f + __expf(-gf));
                float tg = 1.f - 2.f / (__expf(2.f * gg) + 1.f);
                float so = 1.f / (1.f + __expf(-go));
                float cn = sf * c_reg4[j] + si * tg;
                c_reg4[j] = cn;
                float hn = so * (1.f - 2.f / (__expf(2.f * cn) + 1.f));
                float g = gam[sf_row * 36 + hcl];
                outv |= (ull_t)(ushort_t)(f2b(hn * g) + 1) << (16 * j);
            }
            size_t myoff = (size_t)(b0 + sf_row) * 512 + cb * 32 + sf_c4;
            if (t < 255) {
                ushort_t* hnx = hbufs + (size_t)((t + 1) & 7) * 131072;
                __hip_atomic_store((ull_t*)(hnx + myoff), outv,
                                   __ATOMIC_RELAXED, __HIP_MEMORY_SCOPE_AGENT);
            }
            if (t + 4 < 256) {
                ushort_t* hz = hbufs + (size_t)((t + 4) & 7) * 131072;
                __hip_atomic_store((ull_t*)(hz + myoff), 0ULL,
                                   __ATOMIC_RELAXED, __HIP_MEMORY_SCOPE_AGENT);
            }
        }
        __syncthreads();   // drains vmcnt: protects LDS reuse + publishes zeros
    }
}

extern "C" void kernel_launch(void* const* d_in, const int* in_sizes, int n_in,
                              void* d_out, int out_size, void* d_ws, size_t ws_size,
                              hipStream_t stream) {
    const float* data  = (const float*)d_in[0];
    const float* Wih   = (const float*)d_in[1];
    const float* Whh   = (const float*)d_in[2];
    const float* bih   = (const float*)d_in[3];
    const float* bhh   = (const float*)d_in[4];
    const float* Wgh   = (const float*)d_in[5];
    const float* bgh   = (const float*)d_in[6];
    const float* Wgx   = (const float*)d_in[7];
    const float* bgx   = (const float*)d_in[8];
    const float* Whist = (const float*)d_in[9];
    const float* bhist = (const float*)d_in[10];
    const float* Wfeat = (const float*)d_in[11];
    const float* bfeat = (const float*)d_in[12];
    const float* Wcomb = (const float*)d_in[13];
    const float* bcomb = (const float*)d_in[14];
    float* out = (float*)d_out;

    char* ws = (char*)d_ws;
    const size_t NTBC = 256UL * 256 * 64;
    ushort_t* valuesb = (ushort_t*)ws; ws += NTBC * 2;
    ushort_t* masksp  = (ushort_t*)ws; ws += NTBC * 2;
    ushort_t* deltasp = (ushort_t*)ws; ws += NTBC * 2;
    ushort_t* gammax  = (ushort_t*)ws; ws += NTBC * 2;
    ushort_t* alphap  = (ushort_t*)ws; ws += NTBC * 2;
    ushort_t* Wih_b   = (ushort_t*)ws; ws += 2048UL * 128 * 2;
    ushort_t* Whh_b   = (ushort_t*)ws; ws += 2048UL * 512 * 2;
    ushort_t* Wgh_b   = (ushort_t*)ws; ws += 512UL * 64 * 2;
    ushort_t* Whist_b = (ushort_t*)ws; ws += 64UL * 512 * 2;
    ushort_t* Wfeat_b = (ushort_t*)ws; ws += 64UL * 64 * 2;
    ushort_t* hbufs   = (ushort_t*)ws; ws += 8UL * 131072 * 2;  // 2 MB ring
    // total ~44.6 MiB

    k_setup<<<5456, 256, 0, stream>>>(Wih, Whh, Wgh, Whist, Wfeat,
                                      Wih_b, Whh_b, Wgh_b, Whist_b, Wfeat_b,
                                      (ull_t*)hbufs);
    k_pre<<<512, 256, 0, stream>>>(data, Wgx, bgx, valuesb, masksp, deltasp, gammax);
    k_alpha<<<4096, 256, 0, stream>>>(gammax, masksp, Wcomb, bcomb, alphap);
    k_run<<<256, 256, 0, stream>>>(valuesb, masksp, deltasp, alphap,
                                   Wih_b, Whh_b, bih, bhh,
                                   Wgh_b, bgh, Whist_b, bhist,
                                   Wfeat_b, bfeat, hbufs, out);
}